// Round 5
// baseline (24.325 us; speedup 1.0000x reference)
//
#include <hip/hip_runtime.h>

// FractalHilbertTokenizer: images (32,3,1024,1024) f32 -> tokens (32,4096,48) f32 ++ levels(4096)=6.
// Block = (b, level-3 Hilbert tile) covering 8x8 leaves (128x128 px); the tile's 64 token
// indices are consecutive. Reads + LDS scatter -> contiguous 12KB write.
// R5: non-temporal via clang ext-vector float4 (HIP_vector_type rejected by the builtin).

typedef float f4 __attribute__((ext_vector_type(4)));

#define B_ 32
#define MAIN_BLOCKS (B_ * 64)   // 2048
#define LVL_BLOCKS 16

__global__ __launch_bounds__(256) void fht_gather5(const float* __restrict__ img,
                                                   float* __restrict__ out) {
    int bid = blockIdx.x;
    int tid = threadIdx.x;

    if (bid < MAIN_BLOCKS) {
        __shared__ f4 smem[768];               // 64 tokens x 48 floats = 12KB
        int t = bid & 63;                      // tile id (Hilbert levels 0..2)
        int b = bid >> 6;

        // Tile origin via forward ORDERS at l=0,1,2 (packs HW-validated in R0/R3).
        int Ty, Tx;
        {
            int d0 = (t >> 4) & 3, d1 = (t >> 2) & 3, d2 = t & 3;
            int q0 = (0xB4u >> (2 * d0)) & 3;
            int q1 = (0xD2u >> (2 * d1)) & 3;
            int q2 = (0x2Du >> (2 * d2)) & 3;
            Ty = ((q0 >> 1) << 2) | ((q1 >> 1) << 1) | (q2 >> 1);
            Tx = ((q0 & 1) << 2) | ((q1 & 1) << 1) | (q2 & 1);
        }
        int py = Ty << 7;
        int px = Tx << 7;

        // Per-thread decode (same for all 3 planes; only c differs).
        int band = tid >> 5;                   // 0..7  local leaf row
        int i    = (tid >> 3) & 3;             // row within 4x4 patch
        int xl   = tid & 7;                    // 0..7  local leaf col

        const f4* base = reinterpret_cast<const f4*>(img) +
            ((size_t)(b * 3) << 18) +
            ((size_t)(py + band * 16 + i) << 8) +
            (px >> 2) + (xl << 2);

        // Issue all 3 plane loads back-to-back (non-temporal), then scatter to LDS.
        f4 v0 = __builtin_nontemporal_load(base);
        f4 v1 = __builtin_nontemporal_load(base + (1u << 18));
        f4 v2 = __builtin_nontemporal_load(base + (2u << 18));

        // Local Hilbert index from (band, xl): levels 3,4,5 -> inv packs 0x1E,0xB4,0xC9
        // (HW-validated in R2/R3).
        int nl = 0;
        {
            int q, d;
            q = (((band >> 2) & 1) << 1) | ((xl >> 2) & 1);
            d = (0x1Eu >> (2 * q)) & 3;  nl |= d << 4;
            q = (((band >> 1) & 1) << 1) | ((xl >> 1) & 1);
            d = (0xB4u >> (2 * q)) & 3;  nl |= d << 2;
            q = ((band & 1) << 1) | (xl & 1);
            d = (0xC9u >> (2 * q)) & 3;  nl |= d;
        }
        f4* sp = &smem[nl * 12 + i];
        sp[0] = v0;
        sp[4] = v1;
        sp[8] = v2;
        __syncthreads();

        // Contiguous 12,288B block write, non-temporal.
        f4* dst = reinterpret_cast<f4*>(out) + (size_t)bid * 768;
#pragma unroll
        for (int k = 0; k < 3; ++k) {
            int w = tid + (k << 8);
            __builtin_nontemporal_store(smem[w], dst + w);
        }
    } else {
        int n = (bid - MAIN_BLOCKS) * 256 + tid;        // 0..4095
        out[(size_t)B_ * 4096 * 48 + n] = 6.0f;         // levels
    }
}

extern "C" void kernel_launch(void* const* d_in, const int* in_sizes, int n_in,
                              void* d_out, int out_size, void* d_ws, size_t ws_size,
                              hipStream_t stream) {
    const float* img = (const float*)d_in[0];
    float* out = (float*)d_out;
    fht_gather5<<<MAIN_BLOCKS + LVL_BLOCKS, 256, 0, stream>>>(img, out);
}